// Round 9
// baseline (12.298 us; speedup 1.0000x reference)
//
#include <hip/hip_runtime.h>
#include <hip/hip_bf16.h>

#define D_Z 64
#define D_TOTAL 16448
#define NY 16384
#define TJ 64
#define N_YB (NY / TJ)   // 256
#define N_ZB 8

typedef __attribute__((ext_vector_type(8))) short bf16x8;
typedef __attribute__((ext_vector_type(4))) float f32x4;

__device__ __forceinline__ short f2bf(float x) {
    union { __hip_bfloat16 h; short s; } u;
    u.h = __float2bfloat16(x);   // RNE; pairs into v_cvt_pk_bf16_f32
    return u.s;
}

__device__ __forceinline__ bf16x8 packbf(float4 a, float4 b) {
    bf16x8 r = { f2bf(a.x), f2bf(a.y), f2bf(a.z), f2bf(a.w),
                 f2bf(b.x), f2bf(b.y), f2bf(b.z), f2bf(b.w) };
    return r;
}

// Grid: blocks 0..7 -> z-part (16 samples x 64 cols, MFMA).
//       blocks 8..263 -> y-part: 64 y-cols x 128 samples (single round,
//       256 B HBM granules for eps_y/Lyz).
__global__ __launch_bounds__(256, 1) void sv_kernel(
    const float* __restrict__ m,
    const float* __restrict__ Lz,     // tril(64), row-major tril order
    const float* __restrict__ Ly,     // N * 36, per-block tril(8)
    const float* __restrict__ Lyz,    // [NY x 64] row-major
    const float* __restrict__ eps,    // [128, 16448]
    float* __restrict__ out)          // [128, 16448]
{
    __shared__ __align__(16) short zs[128 * 64];  // eps_z bf16 swz   (16 KB)
    __shared__ __align__(16) short ys[128 * 64];  // eps_y tile bf16  (16 KB)
    __shared__ __align__(16) short ls[64 * 64];   // Lyz tile bf16    ( 8 KB)

    const int tid = threadIdx.x;
    const int bb  = blockIdx.x;

    if (bb >= N_ZB) {
        // ================= y-part =================
        const int j0 = (bb - N_ZB) * TJ;
        char* zsb = (char*)zs;
        char* ysb = (char*)ys;
        char* lsb = (char*)ls;

        const int r0z = tid >> 3;          // 0..31
        const int c8z = (tid & 7) << 3;    // 0..56
        const int r0l = tid >> 2;          // 0..63
        const int c16 = (tid & 3) << 4;    // 0,16,32,48
        const int r0y = tid >> 1;          // 0..127
        const int cy  = (tid & 1) << 5;    // 0,32

        // ---- PHASE 1: issue ALL staging loads into registers ----
        float4 rz[4][2], rl[4], ry[8];
        #pragma unroll
        for (int it = 0; it < 4; ++it) {
            const float* p = eps + (size_t)(r0z + (it << 5)) * D_TOTAL + c8z;
            rz[it][0] = *(const float4*)p;
            rz[it][1] = *(const float4*)(p + 4);
        }
        {
            const float* q = Lyz + (size_t)(j0 + r0l) * D_Z + c16;
            #pragma unroll
            for (int i = 0; i < 4; ++i) rl[i] = *(const float4*)(q + 4 * i);
        }
        {
            const float* p = eps + (size_t)r0y * D_TOTAL + D_Z + j0 + cy;
            #pragma unroll
            for (int i = 0; i < 8; ++i) ry[i] = *(const float4*)(p + 4 * i);
        }

        // ---- independent per-lane loads (overlap with staging latency) ----
        const int w    = tid >> 6;
        const int lane = tid & 63;
        const int ln15 = lane & 15;
        const int lg   = lane >> 4;

        float  mj_[4];
        bf16x8 by_[4];
        #pragma unroll
        for (int st = 0; st < 4; ++st) {
            const int jy = j0 + (st << 4) + ln15;
            mj_[st] = m[D_Z + jy];
            const int r = ln15 & 7;
            const float* lyp = Ly + (size_t)(jy >> 3) * 36 + r * (r + 1) / 2;
            bf16x8 by = {0, 0, 0, 0, 0, 0, 0, 0};
            if (lg == (ln15 >> 3)) {
                float lyr[8];
                #pragma unroll
                for (int c = 0; c < 8; ++c) lyr[c] = (c <= r) ? lyp[c] : 0.0f;
                by = packbf(make_float4(lyr[0], lyr[1], lyr[2], lyr[3]),
                            make_float4(lyr[4], lyr[5], lyr[6], lyr[7]));
            }
            by_[st] = by;
        }

        // ---- PHASE 2: cvt + ds_write all staged tiles ----
        #pragma unroll
        for (int it = 0; it < 4; ++it) {
            const int row = r0z + (it << 5);
            *(bf16x8*)(zsb + row * 128 + ((c8z << 1) ^ ((row & 7) << 4))) =
                packbf(rz[it][0], rz[it][1]);
        }
        {
            const int boff = c16 << 1;     // 0,32,64,96
            *(bf16x8*)(lsb + r0l * 128 + ((boff)      ^ ((r0l & 7) << 4))) = packbf(rl[0], rl[1]);
            *(bf16x8*)(lsb + r0l * 128 + ((boff + 16) ^ ((r0l & 7) << 4))) = packbf(rl[2], rl[3]);
        }
        {
            const int boff = cy << 1;      // 0,64
            #pragma unroll
            for (int qq = 0; qq < 4; ++qq) {
                *(bf16x8*)(ysb + r0y * 128 + ((boff + qq * 16) ^ ((r0y & 7) << 4))) =
                    packbf(ry[2 * qq], ry[2 * qq + 1]);
            }
        }
        __syncthreads();

        // ---- A-z fragments (regs, reused across all 4 subtiles) ----
        bf16x8 az[2][2];
        #pragma unroll
        for (int mt = 0; mt < 2; ++mt) {
            const int row = (w << 5) + (mt << 4) + ln15;
            #pragma unroll
            for (int ks = 0; ks < 2; ++ks) {
                az[mt][ks] = *(const bf16x8*)(zsb + row * 128 +
                                (((ks << 6) + (lg << 4)) ^ ((row & 7) << 4)));
            }
        }

        #pragma unroll
        for (int st = 0; st < 4; ++st) {
            const int jg = D_Z + j0 + (st << 4) + ln15;

            // B-z fragments from LDS Lyz panel
            const int brow = (st << 4) + ln15;    // 0..63
            bf16x8 bz[2];
            #pragma unroll
            for (int ks = 0; ks < 2; ++ks) {
                bz[ks] = *(const bf16x8*)(lsb + brow * 128 +
                            (((ks << 6) + (lg << 4)) ^ ((brow & 7) << 4)));
            }

            const float mj = mj_[st];

            #pragma unroll
            for (int mt = 0; mt < 2; ++mt) {
                const int srow = (w << 5) + (mt << 4) + ln15;
                const bf16x8 ay = *(const bf16x8*)(ysb + srow * 128 +
                        (((st << 5) + ((lg & 1) << 4)) ^ ((srow & 7) << 4)));

                f32x4 acc = {0.f, 0.f, 0.f, 0.f};
                acc = __builtin_amdgcn_mfma_f32_16x16x32_bf16(az[mt][0], bz[0], acc, 0, 0, 0);
                acc = __builtin_amdgcn_mfma_f32_16x16x32_bf16(az[mt][1], bz[1], acc, 0, 0, 0);
                acc = __builtin_amdgcn_mfma_f32_16x16x32_bf16(ay,        by_[st], acc, 0, 0, 0);

                const int sbase = (w << 5) + (mt << 4) + (lg << 2);
                #pragma unroll
                for (int reg = 0; reg < 4; ++reg) {
                    out[(size_t)(sbase + reg) * D_TOTAL + jg] = acc[reg] + mj;
                }
            }
        }
    } else {
        // ========== z-part: 16 samples x 64 cols via MFMA (R8 verbatim) ==========
        char* zsb = (char*)zs;
        const int s0 = bb * 16;

        const int w    = tid >> 6;
        const int lane = tid & 63;
        const int ln15 = lane & 15;
        const int lg   = lane >> 4;
        const int j = (w << 4) + ln15;     // out col 0..63

        // stage load into regs first
        float4 sz0, sz1;
        const int row = (tid >> 3) & 15;
        const int c8  = (tid & 7) << 3;
        const bool do_stage = (tid < 128);
        if (do_stage) {
            const float* p = eps + (size_t)(s0 + row) * D_TOTAL + c8;
            sz0 = *(const float4*)p;
            sz1 = *(const float4*)(p + 4);
        }

        // B-frags: Lz row j, zero-masked beyond the triangle (k > j)
        const float* lzr = Lz + j * (j + 1) / 2;
        bf16x8 bz[2];
        #pragma unroll
        for (int ks = 0; ks < 2; ++ks) {
            float v[8];
            #pragma unroll
            for (int e = 0; e < 8; ++e) {
                const int k = (ks << 5) + (lg << 3) + e;
                v[e] = (k <= j) ? lzr[k] : 0.0f;
            }
            bz[ks] = packbf(make_float4(v[0], v[1], v[2], v[3]),
                            make_float4(v[4], v[5], v[6], v[7]));
        }

        if (do_stage) {
            *(bf16x8*)(zsb + row * 128 + ((c8 << 1) ^ ((row & 7) << 4))) =
                packbf(sz0, sz1);
        }
        __syncthreads();

        // A-frags: eps_z rows from LDS
        bf16x8 az[2];
        #pragma unroll
        for (int ks = 0; ks < 2; ++ks) {
            az[ks] = *(const bf16x8*)(zsb + ln15 * 128 +
                        (((ks << 6) + (lg << 4)) ^ ((ln15 & 7) << 4)));
        }

        f32x4 acc = {0.f, 0.f, 0.f, 0.f};
        acc = __builtin_amdgcn_mfma_f32_16x16x32_bf16(az[0], bz[0], acc, 0, 0, 0);
        acc = __builtin_amdgcn_mfma_f32_16x16x32_bf16(az[1], bz[1], acc, 0, 0, 0);

        const float mj = m[j];
        #pragma unroll
        for (int reg = 0; reg < 4; ++reg) {
            out[(size_t)(s0 + (lg << 2) + reg) * D_TOTAL + j] = acc[reg] + mj;
        }
    }
}

extern "C" void kernel_launch(void* const* d_in, const int* in_sizes, int n_in,
                              void* d_out, int out_size, void* d_ws, size_t ws_size,
                              hipStream_t stream) {
    const float* m   = (const float*)d_in[0];
    const float* Lz  = (const float*)d_in[1];
    const float* Ly  = (const float*)d_in[2];
    const float* Lyz = (const float*)d_in[3];
    const float* eps = (const float*)d_in[4];
    float* out = (float*)d_out;

    dim3 grid(N_ZB + N_YB);  // 264
    dim3 block(256);
    hipLaunchKernelGGL(sv_kernel, grid, block, 0, stream,
                       m, Lz, Ly, Lyz, eps, out);
}

// Round 10
// 11.939 us; speedup vs baseline: 1.0301x; 1.0301x over previous
//
#include <hip/hip_runtime.h>
#include <hip/hip_bf16.h>

#define D_Z 64
#define D_TOTAL 16448
#define NY 16384
#define TJ 32
#define N_YB (NY / TJ)   // 512  (grid = exactly 2 blocks/CU, no stragglers)
#define N_ZCH 8          // z-part folded into y-blocks 0..7

typedef __attribute__((ext_vector_type(8))) short bf16x8;
typedef __attribute__((ext_vector_type(4))) float f32x4;

__device__ __forceinline__ short f2bf(float x) {
    union { __hip_bfloat16 h; short s; } u;
    u.h = __float2bfloat16(x);   // RNE; pairs into v_cvt_pk_bf16_f32
    return u.s;
}

__device__ __forceinline__ bf16x8 packbf(float4 a, float4 b) {
    bf16x8 r = { f2bf(a.x), f2bf(a.y), f2bf(a.z), f2bf(a.w),
                 f2bf(b.x), f2bf(b.y), f2bf(b.z), f2bf(b.w) };
    return r;
}

// Grid: exactly 512 blocks; block bb handles y-cols [bb*32, bb*32+32).
// Blocks 0..7 additionally compute the z-part chunk bb (16 samples x 64 cols),
// reusing the full 128-row eps_z tile already staged in LDS.
__global__ __launch_bounds__(256, 2) void sv_kernel(
    const float* __restrict__ m,
    const float* __restrict__ Lz,     // tril(64), row-major tril order
    const float* __restrict__ Ly,     // N * 36, per-block tril(8)
    const float* __restrict__ Lyz,    // [NY x 64] row-major
    const float* __restrict__ eps,    // [128, 16448]
    float* __restrict__ out)          // [128, 16448]
{
    __shared__ __align__(16) short zs[128 * 64];  // eps_z bf16 swz  (16 KB)
    __shared__ __align__(16) short ys[128 * 32];  // eps_y tile bf16 ( 8 KB)
    __shared__ __align__(16) short ls[32 * 64];   // Lyz tile bf16   ( 4 KB)

    const int tid = threadIdx.x;
    const int bb  = blockIdx.x;
    const int j0  = bb * TJ;

    char* zsb = (char*)zs;
    char* ysb = (char*)ys;
    char* lsb = (char*)ls;

    const int r0z = tid >> 3;          // 0..31
    const int c8z = (tid & 7) << 3;    // 0..56
    const int r0y = tid >> 2;          // 0..63
    const int c8y = (tid & 3) << 3;    // 0,8,16,24

    // ---- PHASE 1: issue ALL staging loads into registers ----
    float4 rz[4][2], rl[2], ry[2][2];
    #pragma unroll
    for (int it = 0; it < 4; ++it) {
        const float* p = eps + (size_t)(r0z + (it << 5)) * D_TOTAL + c8z;
        rz[it][0] = *(const float4*)p;
        rz[it][1] = *(const float4*)(p + 4);
    }
    {
        const float* q = Lyz + (size_t)(j0 + r0z) * D_Z + c8z;
        rl[0] = *(const float4*)q;
        rl[1] = *(const float4*)(q + 4);
    }
    #pragma unroll
    for (int it = 0; it < 2; ++it) {
        const float* p = eps + (size_t)(r0y + (it << 6)) * D_TOTAL + D_Z + j0 + c8y;
        ry[it][0] = *(const float4*)p;
        ry[it][1] = *(const float4*)(p + 4);
    }

    // ---- independent per-lane loads (overlap with staging latency) ----
    const int w    = tid >> 6;
    const int lane = tid & 63;
    const int ln15 = lane & 15;
    const int lg   = lane >> 4;

    float  mj_[2];
    bf16x8 by_[2];
    #pragma unroll
    for (int st = 0; st < 2; ++st) {
        const int jy = j0 + (st << 4) + ln15;
        mj_[st] = m[D_Z + jy];
        const int r = ln15 & 7;
        const float* lyp = Ly + (size_t)(jy >> 3) * 36 + r * (r + 1) / 2;
        bf16x8 by = {0, 0, 0, 0, 0, 0, 0, 0};
        if (lg == (ln15 >> 3)) {
            float lyr[8];
            #pragma unroll
            for (int c = 0; c < 8; ++c) lyr[c] = (c <= r) ? lyp[c] : 0.0f;
            by = packbf(make_float4(lyr[0], lyr[1], lyr[2], lyr[3]),
                        make_float4(lyr[4], lyr[5], lyr[6], lyr[7]));
        }
        by_[st] = by;
    }

    // ---- PHASE 2: cvt + ds_write all staged tiles ----
    #pragma unroll
    for (int it = 0; it < 4; ++it) {
        const int row = r0z + (it << 5);
        *(bf16x8*)(zsb + row * 128 + ((c8z << 1) ^ ((row & 7) << 4))) =
            packbf(rz[it][0], rz[it][1]);
    }
    *(bf16x8*)(lsb + r0z * 128 + ((c8z << 1) ^ ((r0z & 7) << 4))) =
        packbf(rl[0], rl[1]);
    #pragma unroll
    for (int it = 0; it < 2; ++it) {
        const int row = r0y + (it << 6);
        *(bf16x8*)(ysb + row * 64 + ((c8y << 1) ^ ((row & 3) << 4))) =
            packbf(ry[it][0], ry[it][1]);
    }
    __syncthreads();

    // ---- A-z fragments (regs, reused across both subtiles) ----
    bf16x8 az[2][2];
    #pragma unroll
    for (int mt = 0; mt < 2; ++mt) {
        const int row = (w << 5) + (mt << 4) + ln15;
        #pragma unroll
        for (int ks = 0; ks < 2; ++ks) {
            az[mt][ks] = *(const bf16x8*)(zsb + row * 128 +
                            (((ks << 6) + (lg << 4)) ^ ((row & 7) << 4)));
        }
    }

    #pragma unroll
    for (int st = 0; st < 2; ++st) {
        const int jg = D_Z + j0 + (st << 4) + ln15;

        // B-z fragments from LDS Lyz panel
        const int brow = (st << 4) + ln15;
        bf16x8 bz[2];
        #pragma unroll
        for (int ks = 0; ks < 2; ++ks) {
            bz[ks] = *(const bf16x8*)(lsb + brow * 128 +
                        (((ks << 6) + (lg << 4)) ^ ((brow & 7) << 4)));
        }

        const float mj = mj_[st];

        #pragma unroll
        for (int mt = 0; mt < 2; ++mt) {
            const int srow = (w << 5) + (mt << 4) + ln15;
            const bf16x8 ay = *(const bf16x8*)(ysb + srow * 64 +
                    (((st << 5) + ((lg & 1) << 4)) ^ ((srow & 3) << 4)));

            f32x4 acc = {0.f, 0.f, 0.f, 0.f};
            acc = __builtin_amdgcn_mfma_f32_16x16x32_bf16(az[mt][0], bz[0], acc, 0, 0, 0);
            acc = __builtin_amdgcn_mfma_f32_16x16x32_bf16(az[mt][1], bz[1], acc, 0, 0, 0);
            acc = __builtin_amdgcn_mfma_f32_16x16x32_bf16(ay,        by_[st], acc, 0, 0, 0);

            const int sbase = (w << 5) + (mt << 4) + (lg << 2);
            #pragma unroll
            for (int reg = 0; reg < 4; ++reg) {
                out[(size_t)(sbase + reg) * D_TOTAL + jg] = acc[reg] + mj;
            }
        }
    }

    // ---- folded z-part: blocks 0..7, chunk bb (16 samples x 64 cols) ----
    if (bb < N_ZCH) {
        const int s0 = bb << 4;
        const int j  = (w << 4) + ln15;    // out col 0..63

        // B-frags: Lz row j, zero-masked beyond the triangle (k > j)
        const float* lzr = Lz + j * (j + 1) / 2;
        bf16x8 bzz[2];
        #pragma unroll
        for (int ks = 0; ks < 2; ++ks) {
            float v[8];
            #pragma unroll
            for (int e = 0; e < 8; ++e) {
                const int k = (ks << 5) + (lg << 3) + e;
                v[e] = (k <= j) ? lzr[k] : 0.0f;
            }
            bzz[ks] = packbf(make_float4(v[0], v[1], v[2], v[3]),
                             make_float4(v[4], v[5], v[6], v[7]));
        }

        // A-frags: eps_z rows s0..s0+15 straight from the already-staged zs
        bf16x8 azz[2];
        #pragma unroll
        for (int ks = 0; ks < 2; ++ks) {
            const int row = s0 + ln15;
            azz[ks] = *(const bf16x8*)(zsb + row * 128 +
                        (((ks << 6) + (lg << 4)) ^ ((row & 7) << 4)));
        }

        f32x4 acc = {0.f, 0.f, 0.f, 0.f};
        acc = __builtin_amdgcn_mfma_f32_16x16x32_bf16(azz[0], bzz[0], acc, 0, 0, 0);
        acc = __builtin_amdgcn_mfma_f32_16x16x32_bf16(azz[1], bzz[1], acc, 0, 0, 0);

        const float mj = m[j];
        #pragma unroll
        for (int reg = 0; reg < 4; ++reg) {
            out[(size_t)(s0 + (lg << 2) + reg) * D_TOTAL + j] = acc[reg] + mj;
        }
    }
}

extern "C" void kernel_launch(void* const* d_in, const int* in_sizes, int n_in,
                              void* d_out, int out_size, void* d_ws, size_t ws_size,
                              hipStream_t stream) {
    const float* m   = (const float*)d_in[0];
    const float* Lz  = (const float*)d_in[1];
    const float* Ly  = (const float*)d_in[2];
    const float* Lyz = (const float*)d_in[3];
    const float* eps = (const float*)d_in[4];
    float* out = (float*)d_out;

    dim3 grid(N_YB);  // 512 exactly
    dim3 block(256);
    hipLaunchKernelGGL(sv_kernel, grid, block, 0, stream,
                       m, Lz, Ly, Lyz, eps, out);
}

// Round 11
// 10.204 us; speedup vs baseline: 1.2052x; 1.1701x over previous
//
#include <hip/hip_runtime.h>
#include <hip/hip_bf16.h>

#define D_Z 64
#define D_TOTAL 16448
#define NY 16384
#define TJ 32
#define N_YB (NY / TJ)   // 512
#define N_ZB 8

typedef __attribute__((ext_vector_type(8))) short bf16x8;
typedef __attribute__((ext_vector_type(4))) float f32x4;

__device__ __forceinline__ short f2bf(float x) {
    union { __hip_bfloat16 h; short s; } u;
    u.h = __float2bfloat16(x);   // RNE; pairs into v_cvt_pk_bf16_f32
    return u.s;
}

__device__ __forceinline__ bf16x8 packbf(float4 a, float4 b) {
    bf16x8 r = { f2bf(a.x), f2bf(a.y), f2bf(a.z), f2bf(a.w),
                 f2bf(b.x), f2bf(b.y), f2bf(b.z), f2bf(b.w) };
    return r;
}

// R8 structure (best measured: 10.69-10.76 us) + nontemporal out stores
// (streaming, no RFO / write-allocate on partial-line stores).
// Grid: blocks 0..7 -> z-part (16 samples x 64 cols, MFMA).
//       blocks 8..519 -> y-part: 32 y-cols x 128 samples.
__global__ __launch_bounds__(256, 2) void sv_kernel(
    const float* __restrict__ m,
    const float* __restrict__ Lz,     // tril(64), row-major tril order
    const float* __restrict__ Ly,     // N * 36, per-block tril(8)
    const float* __restrict__ Lyz,    // [NY x 64] row-major
    const float* __restrict__ eps,    // [128, 16448]
    float* __restrict__ out)          // [128, 16448]
{
    __shared__ __align__(16) short zs[128 * 64];  // eps_z bf16 swz  (16 KB)
    __shared__ __align__(16) short ys[128 * 32];  // eps_y tile bf16 ( 8 KB)
    __shared__ __align__(16) short ls[32 * 64];   // Lyz tile bf16   ( 4 KB)

    const int tid = threadIdx.x;
    const int bb  = blockIdx.x;

    if (bb >= N_ZB) {
        // ================= y-part =================
        const int j0 = (bb - N_ZB) * TJ;
        char* zsb = (char*)zs;
        char* ysb = (char*)ys;
        char* lsb = (char*)ls;

        const int r0z = tid >> 3;          // 0..31
        const int c8z = (tid & 7) << 3;    // 0..56
        const int r0y = tid >> 2;          // 0..63
        const int c8y = (tid & 3) << 3;    // 0,8,16,24

        // ---- PHASE 1: issue ALL staging loads into registers ----
        float4 rz[4][2], rl[2], ry[2][2];
        #pragma unroll
        for (int it = 0; it < 4; ++it) {
            const float* p = eps + (size_t)(r0z + (it << 5)) * D_TOTAL + c8z;
            rz[it][0] = *(const float4*)p;
            rz[it][1] = *(const float4*)(p + 4);
        }
        {
            const float* q = Lyz + (size_t)(j0 + r0z) * D_Z + c8z;
            rl[0] = *(const float4*)q;
            rl[1] = *(const float4*)(q + 4);
        }
        #pragma unroll
        for (int it = 0; it < 2; ++it) {
            const float* p = eps + (size_t)(r0y + (it << 6)) * D_TOTAL + D_Z + j0 + c8y;
            ry[it][0] = *(const float4*)p;
            ry[it][1] = *(const float4*)(p + 4);
        }

        // ---- independent per-lane loads (overlap with staging latency) ----
        const int w    = tid >> 6;
        const int lane = tid & 63;
        const int ln15 = lane & 15;
        const int lg   = lane >> 4;

        float  mj_[2];
        bf16x8 by_[2];
        #pragma unroll
        for (int st = 0; st < 2; ++st) {
            const int jy = j0 + (st << 4) + ln15;
            mj_[st] = m[D_Z + jy];
            const int r = ln15 & 7;
            const float* lyp = Ly + (size_t)(jy >> 3) * 36 + r * (r + 1) / 2;
            bf16x8 by = {0, 0, 0, 0, 0, 0, 0, 0};
            if (lg == (ln15 >> 3)) {
                float lyr[8];
                #pragma unroll
                for (int c = 0; c < 8; ++c) lyr[c] = (c <= r) ? lyp[c] : 0.0f;
                by = packbf(make_float4(lyr[0], lyr[1], lyr[2], lyr[3]),
                            make_float4(lyr[4], lyr[5], lyr[6], lyr[7]));
            }
            by_[st] = by;
        }

        // ---- PHASE 2: cvt + ds_write all staged tiles ----
        #pragma unroll
        for (int it = 0; it < 4; ++it) {
            const int row = r0z + (it << 5);
            *(bf16x8*)(zsb + row * 128 + ((c8z << 1) ^ ((row & 7) << 4))) =
                packbf(rz[it][0], rz[it][1]);
        }
        *(bf16x8*)(lsb + r0z * 128 + ((c8z << 1) ^ ((r0z & 7) << 4))) =
            packbf(rl[0], rl[1]);
        #pragma unroll
        for (int it = 0; it < 2; ++it) {
            const int row = r0y + (it << 6);
            *(bf16x8*)(ysb + row * 64 + ((c8y << 1) ^ ((row & 3) << 4))) =
                packbf(ry[it][0], ry[it][1]);
        }
        __syncthreads();

        // ---- A-z fragments (regs, reused across both subtiles) ----
        bf16x8 az[2][2];
        #pragma unroll
        for (int mt = 0; mt < 2; ++mt) {
            const int row = (w << 5) + (mt << 4) + ln15;
            #pragma unroll
            for (int ks = 0; ks < 2; ++ks) {
                az[mt][ks] = *(const bf16x8*)(zsb + row * 128 +
                                (((ks << 6) + (lg << 4)) ^ ((row & 7) << 4)));
            }
        }

        #pragma unroll
        for (int st = 0; st < 2; ++st) {
            const int jy = j0 + (st << 4) + ln15;
            const int jg = D_Z + jy;

            // B-z fragments from LDS Lyz panel
            const int brow = (st << 4) + ln15;
            bf16x8 bz[2];
            #pragma unroll
            for (int ks = 0; ks < 2; ++ks) {
                bz[ks] = *(const bf16x8*)(lsb + brow * 128 +
                            (((ks << 6) + (lg << 4)) ^ ((brow & 7) << 4)));
            }

            const float mj = mj_[st];

            #pragma unroll
            for (int mt = 0; mt < 2; ++mt) {
                const int srow = (w << 5) + (mt << 4) + ln15;
                const bf16x8 ay = *(const bf16x8*)(ysb + srow * 64 +
                        (((st << 5) + ((lg & 1) << 4)) ^ ((srow & 3) << 4)));

                f32x4 acc = {0.f, 0.f, 0.f, 0.f};
                acc = __builtin_amdgcn_mfma_f32_16x16x32_bf16(az[mt][0], bz[0], acc, 0, 0, 0);
                acc = __builtin_amdgcn_mfma_f32_16x16x32_bf16(az[mt][1], bz[1], acc, 0, 0, 0);
                acc = __builtin_amdgcn_mfma_f32_16x16x32_bf16(ay,        by_[st], acc, 0, 0, 0);

                const int sbase = (w << 5) + (mt << 4) + (lg << 2);
                #pragma unroll
                for (int reg = 0; reg < 4; ++reg) {
                    __builtin_nontemporal_store(acc[reg] + mj,
                        &out[(size_t)(sbase + reg) * D_TOTAL + jg]);
                }
            }
        }
    } else {
        // ========== z-part: 16 samples x 64 cols via MFMA ==========
        char* zsb = (char*)zs;
        const int s0 = bb * 16;

        const int w    = tid >> 6;
        const int lane = tid & 63;
        const int ln15 = lane & 15;
        const int lg   = lane >> 4;
        const int j = (w << 4) + ln15;     // out col 0..63

        // stage load into regs first
        float4 sz0, sz1;
        const int row = (tid >> 3) & 15;
        const int c8  = (tid & 7) << 3;
        const bool do_stage = (tid < 128);
        if (do_stage) {
            const float* p = eps + (size_t)(s0 + row) * D_TOTAL + c8;
            sz0 = *(const float4*)p;
            sz1 = *(const float4*)(p + 4);
        }

        // B-frags: Lz row j, zero-masked beyond the triangle (k > j)
        const float* lzr = Lz + j * (j + 1) / 2;
        bf16x8 bz[2];
        #pragma unroll
        for (int ks = 0; ks < 2; ++ks) {
            float v[8];
            #pragma unroll
            for (int e = 0; e < 8; ++e) {
                const int k = (ks << 5) + (lg << 3) + e;
                v[e] = (k <= j) ? lzr[k] : 0.0f;
            }
            bz[ks] = packbf(make_float4(v[0], v[1], v[2], v[3]),
                            make_float4(v[4], v[5], v[6], v[7]));
        }

        if (do_stage) {
            *(bf16x8*)(zsb + row * 128 + ((c8 << 1) ^ ((row & 7) << 4))) =
                packbf(sz0, sz1);
        }
        __syncthreads();

        // A-frags: eps_z rows from LDS
        bf16x8 az[2];
        #pragma unroll
        for (int ks = 0; ks < 2; ++ks) {
            az[ks] = *(const bf16x8*)(zsb + ln15 * 128 +
                        (((ks << 6) + (lg << 4)) ^ ((ln15 & 7) << 4)));
        }

        f32x4 acc = {0.f, 0.f, 0.f, 0.f};
        acc = __builtin_amdgcn_mfma_f32_16x16x32_bf16(az[0], bz[0], acc, 0, 0, 0);
        acc = __builtin_amdgcn_mfma_f32_16x16x32_bf16(az[1], bz[1], acc, 0, 0, 0);

        const float mj = m[j];
        #pragma unroll
        for (int reg = 0; reg < 4; ++reg) {
            __builtin_nontemporal_store(acc[reg] + mj,
                &out[(size_t)(s0 + (lg << 2) + reg) * D_TOTAL + j]);
        }
    }
}

extern "C" void kernel_launch(void* const* d_in, const int* in_sizes, int n_in,
                              void* d_out, int out_size, void* d_ws, size_t ws_size,
                              hipStream_t stream) {
    const float* m   = (const float*)d_in[0];
    const float* Lz  = (const float*)d_in[1];
    const float* Ly  = (const float*)d_in[2];
    const float* Lyz = (const float*)d_in[3];
    const float* eps = (const float*)d_in[4];
    float* out = (float*)d_out;

    dim3 grid(N_ZB + N_YB);  // 520
    dim3 block(256);
    hipLaunchKernelGGL(sv_kernel, grid, block, 0, stream,
                       m, Lz, Ly, Lyz, eps, out);
}